// Round 2
// baseline (956.682 us; speedup 1.0000x reference)
//
#include <hip/hip_runtime.h>
#include <cstdint>

// ---------------------------------------------------------------------------
// Edge2NodeProp: e = (rbf @ W_rbf^T) * x ; h = segment_sum(e, idx_i);
//                h = swish(h@W1^T+b1) x3; out = h @ W_out^T
//
// R2 = R1 resubmit (container-level failure last round) with one fix:
//   k_gather had __launch_bounds__(256,8) -> 32-VGPR cap -> scratch spill on
//   the hot loop. Now default bounds.
// Design: replace atomic scatter-add (320 MB HBM write-through @1.47 TB/s)
//   with on-device CSR build (hist -> scan -> scatter ids) + per-node gather.
// ---------------------------------------------------------------------------

// ---------------- CSR build ----------------

__global__ __launch_bounds__(256) void k_hist(
    const int* __restrict__ idx, int* __restrict__ counts, int n_edges)
{
    const int i = blockIdx.x * blockDim.x + threadIdx.x;
    const int stride = gridDim.x * blockDim.x;
    for (int e = i; e < n_edges; e += stride)
        atomicAdd(&counts[idx[e]], 1);
}

// Per-block inclusive scan of a 256-chunk; writes local-exclusive offsets and
// the block total.
__global__ __launch_bounds__(256) void k_scan1(
    const int* __restrict__ counts, int* __restrict__ offsets,
    int* __restrict__ blocksum, int n_nodes)
{
    __shared__ int sh[256];
    const int t = threadIdx.x;
    const int i = blockIdx.x * 256 + t;
    const int v = (i < n_nodes) ? counts[i] : 0;
    sh[t] = v;
    __syncthreads();
    for (int off = 1; off < 256; off <<= 1) {
        const int add = (t >= off) ? sh[t - off] : 0;
        __syncthreads();
        sh[t] += add;
        __syncthreads();
    }
    if (i < n_nodes) offsets[i] = sh[t] - v;   // exclusive, block-local
    if (t == 255) blocksum[blockIdx.x] = sh[255];
}

// Single-block exclusive scan of block sums (nb <= 512; N=100K -> nb=391).
__global__ __launch_bounds__(512) void k_scan2(int* __restrict__ blocksum, int nb)
{
    __shared__ int sh[512];
    const int t = threadIdx.x;
    const int v = (t < nb) ? blocksum[t] : 0;
    sh[t] = v;
    __syncthreads();
    for (int off = 1; off < 512; off <<= 1) {
        const int add = (t >= off) ? sh[t - off] : 0;
        __syncthreads();
        sh[t] += add;
        __syncthreads();
    }
    if (t < nb) blocksum[t] = sh[t] - v;       // exclusive block base
}

__global__ __launch_bounds__(256) void k_addbase(
    int* __restrict__ offsets, const int* __restrict__ blocksum,
    int* __restrict__ cursor, int n_nodes, int n_edges)
{
    const int i = blockIdx.x * 256 + threadIdx.x;
    if (i < n_nodes) {
        const int o = offsets[i] + blocksum[blockIdx.x];
        offsets[i] = o;
        cursor[i]  = o;
    }
    if (i == 0) offsets[n_nodes] = n_edges;
}

__global__ __launch_bounds__(256) void k_scatter(
    const int* __restrict__ idx, int* __restrict__ cursor,
    int* __restrict__ perm, int n_edges)
{
    const int i = blockIdx.x * blockDim.x + threadIdx.x;
    const int stride = gridDim.x * blockDim.x;
    for (int e = i; e < n_edges; e += stride) {
        const int pos = atomicAdd(&cursor[idx[e]], 1);
        perm[pos] = e;
    }
}

// ---------------- gather: one wave per node, lane = dim ----------------
__global__ __launch_bounds__(256) void k_gather(
    const float* __restrict__ x,       // (E,64)
    const float* __restrict__ rbf,     // (E,16)
    const int*   __restrict__ offsets, // (N+1)
    const int*   __restrict__ perm,    // (E)
    const float* __restrict__ Wrbf,    // (64,16)
    float* __restrict__ hacc,          // (N,64)
    int n_nodes)
{
    const int lane = threadIdx.x & 63;
    const int n    = blockIdx.x * (blockDim.x >> 6) + (threadIdx.x >> 6);
    if (n >= n_nodes) return;

    // Per-lane W_rbf row (16 f32 = 64B contiguous).
    float w[16];
    {
        const float4* wp = (const float4*)(Wrbf + (size_t)lane * 16);
        float4 a = wp[0], b = wp[1], c = wp[2], d = wp[3];
        w[0]=a.x; w[1]=a.y; w[2]=a.z; w[3]=a.w;
        w[4]=b.x; w[5]=b.y; w[6]=b.z; w[7]=b.w;
        w[8]=c.x; w[9]=c.y; w[10]=c.z; w[11]=c.w;
        w[12]=d.x; w[13]=d.y; w[14]=d.z; w[15]=d.w;
    }

    const int s     = offsets[n];
    const int e_end = offsets[n + 1];

    float acc = 0.0f;
    int e = (s < e_end) ? perm[s] : 0;           // prefetched edge id
    for (int j = s; j < e_end; ++j) {
        const int e_nxt = (j + 1 < e_end) ? perm[j + 1] : 0;

        const float4* rp = (const float4*)(rbf + (size_t)e * 16);
        float4 r0 = rp[0], r1 = rp[1], r2 = rp[2], r3 = rp[3];
        const float xv = x[(size_t)e * 64 + lane];

        float g = 0.0f;
        g = fmaf(r0.x, w[0],  g); g = fmaf(r0.y, w[1],  g);
        g = fmaf(r0.z, w[2],  g); g = fmaf(r0.w, w[3],  g);
        g = fmaf(r1.x, w[4],  g); g = fmaf(r1.y, w[5],  g);
        g = fmaf(r1.z, w[6],  g); g = fmaf(r1.w, w[7],  g);
        g = fmaf(r2.x, w[8],  g); g = fmaf(r2.y, w[9],  g);
        g = fmaf(r2.z, w[10], g); g = fmaf(r2.w, w[11], g);
        g = fmaf(r3.x, w[12], g); g = fmaf(r3.y, w[13], g);
        g = fmaf(r3.z, w[14], g); g = fmaf(r3.w, w[15], g);

        acc = fmaf(g, xv, acc);
        e = e_nxt;
    }
    hacc[(size_t)n * 64 + lane] = acc;
}

// ---------------- fallback atomic scatter (verified path, used only if
// workspace is too small for the CSR buffers) ----------------
__global__ __launch_bounds__(256) void edge_kernel(
    const float* __restrict__ x, const float* __restrict__ rbf,
    const int* __restrict__ idx, const float* __restrict__ Wrbf,
    float* __restrict__ hacc, int n_edges, int n_nodes)
{
    const int lane   = threadIdx.x & 63;
    const int wave   = blockIdx.x * (blockDim.x >> 6) + (threadIdx.x >> 6);
    const int nwaves = gridDim.x * (blockDim.x >> 6);

    float w[16];
    {
        const float4* wp = (const float4*)(Wrbf + (size_t)lane * 16);
        float4 a = wp[0], b = wp[1], c = wp[2], d = wp[3];
        w[0]=a.x; w[1]=a.y; w[2]=a.z; w[3]=a.w;
        w[4]=b.x; w[5]=b.y; w[6]=b.z; w[7]=b.w;
        w[8]=c.x; w[9]=c.y; w[10]=c.z; w[11]=c.w;
        w[12]=d.x; w[13]=d.y; w[14]=d.z; w[15]=d.w;
    }

    for (int e = wave; e < n_edges; e += nwaves) {
        const int node = idx[e];
        const float4* rp = (const float4*)(rbf + (size_t)e * 16);
        float4 r0 = rp[0], r1 = rp[1], r2 = rp[2], r3 = rp[3];
        float rv[16] = { r0.x, r0.y, r0.z, r0.w, r1.x, r1.y, r1.z, r1.w,
                         r2.x, r2.y, r2.z, r2.w, r3.x, r3.y, r3.z, r3.w };
        float g = 0.0f;
#pragma unroll
        for (int r = 0; r < 16; ++r) g = fmaf(rv[r], w[r], g);
        const float xv = x[(size_t)e * 64 + lane];
        if ((unsigned)node < (unsigned)n_nodes)
            atomicAdd(&hacc[(size_t)node * 64 + lane], g * xv);
    }
}

// ---------------------------------------------------------------------------
// Phase 2: node MLP. One wave per node, lane = dim. (unchanged, known-good)
// ---------------------------------------------------------------------------
__device__ __forceinline__ float mlp_layer(const float* __restrict__ WT,
                                           const float* __restrict__ bias,
                                           float h, int lane)
{
    float acc = bias[lane];
#pragma unroll
    for (int k = 0; k < 64; ++k) {
        const float wk = WT[k * 64 + lane];
        const float hk = __int_as_float(
            __builtin_amdgcn_readlane(__float_as_int(h), k));
        acc = fmaf(wk, hk, acc);
    }
    return acc / (1.0f + __expf(-acc));   // swish
}

__global__ __launch_bounds__(256) void node_kernel(
    const float* __restrict__ hacc,
    const float* __restrict__ W1, const float* __restrict__ b1,
    const float* __restrict__ W2, const float* __restrict__ b2,
    const float* __restrict__ W3, const float* __restrict__ b3,
    const float* __restrict__ Wout,
    float* __restrict__ out, int n_nodes)
{
    __shared__ float WT[3][64 * 64];
    __shared__ float bs[3][64];
    __shared__ float wo[64];

    const int t = threadIdx.x;
    for (int i = t; i < 64 * 64; i += 256) {
        const int d = i & 63;
        const int k = i >> 6;
        WT[0][k * 64 + d] = W1[d * 64 + k];
        WT[1][k * 64 + d] = W2[d * 64 + k];
        WT[2][k * 64 + d] = W3[d * 64 + k];
    }
    if (t < 64) {
        bs[0][t] = b1[t]; bs[1][t] = b2[t]; bs[2][t] = b3[t];
        wo[t] = Wout[t];
    }
    __syncthreads();

    const int lane   = t & 63;
    const int wave   = blockIdx.x * (blockDim.x >> 6) + (t >> 6);
    const int nwaves = gridDim.x * (blockDim.x >> 6);

    for (int node = wave; node < n_nodes; node += nwaves) {
        float h = hacc[(size_t)node * 64 + lane];
        h = mlp_layer(WT[0], bs[0], h, lane);
        h = mlp_layer(WT[1], bs[1], h, lane);
        h = mlp_layer(WT[2], bs[2], h, lane);

        float v = wo[lane] * h;
#pragma unroll
        for (int off = 32; off >= 1; off >>= 1) v += __shfl_xor(v, off, 64);
        if (lane == 0) out[node] = v;
    }
}

// ---------------------------------------------------------------------------
extern "C" void kernel_launch(void* const* d_in, const int* in_sizes, int n_in,
                              void* d_out, int out_size, void* d_ws, size_t ws_size,
                              hipStream_t stream)
{
    const float* x    = (const float*)d_in[0];
    const float* rbf  = (const float*)d_in[1];
    const int*   idx  = (const int*)d_in[2];
    const float* Wrbf = (const float*)d_in[4];
    const float* W1   = (const float*)d_in[5];
    const float* b1   = (const float*)d_in[6];
    const float* W2   = (const float*)d_in[7];
    const float* b2   = (const float*)d_in[8];
    const float* W3   = (const float*)d_in[9];
    const float* b3   = (const float*)d_in[10];
    const float* Wout = (const float*)d_in[11];

    const int n_edges = in_sizes[0] / 64;
    const int n_nodes = out_size;   // OUT_DIM == 1

    // Workspace layout (64-int = 256B aligned blocks):
    const size_t N_pad = ((size_t)n_nodes + 1 + 63) & ~(size_t)63;
    const size_t E_pad = ((size_t)n_edges + 63) & ~(size_t)63;
    int*   counts = (int*)d_ws;              // N  (reused as cursor)
    int*   offs   = counts + N_pad;          // N+1
    int*   bsum   = offs + N_pad;            // <=512
    int*   perm   = bsum + 512;              // E
    float* hacc   = (float*)(perm + E_pad);  // N*64 f32

    const size_t need = (2 * N_pad + 512 + E_pad) * sizeof(int)
                      + (size_t)n_nodes * 64 * sizeof(float);

    const int NB = (n_nodes + 255) / 256;    // 391 for N=100K (<=512)

    if (ws_size >= need && NB <= 512) {
        // ---- CSR build + gather path ----
        hipMemsetAsync(counts, 0, (size_t)n_nodes * sizeof(int), stream);
        k_hist   <<<2048, 256, 0, stream>>>(idx, counts, n_edges);
        k_scan1  <<<NB,   256, 0, stream>>>(counts, offs, bsum, n_nodes);
        k_scan2  <<<1,    512, 0, stream>>>(bsum, NB);
        k_addbase<<<NB,   256, 0, stream>>>(offs, bsum, counts, n_nodes, n_edges);
        k_scatter<<<2048, 256, 0, stream>>>(idx, counts, perm, n_edges);

        const int gblocks = (n_nodes + 3) / 4;    // 4 waves/block, 1 node/wave
        k_gather<<<gblocks, 256, 0, stream>>>(x, rbf, offs, perm, Wrbf,
                                              hacc, n_nodes);
    } else {
        // ---- fallback: verified atomic path ----
        hacc = (float*)d_ws;
        hipMemsetAsync(hacc, 0, (size_t)n_nodes * 64 * sizeof(float), stream);
        edge_kernel<<<8192, 256, 0, stream>>>(x, rbf, idx, Wrbf, hacc,
                                              n_edges, n_nodes);
    }

    node_kernel<<<2048, 256, 0, stream>>>(hacc, W1, b1, W2, b2, W3, b3, Wout,
                                          (float*)d_out, n_nodes);
}